// Round 8
// baseline (186.039 us; speedup 1.0000x reference)
//
#include <hip/hip_runtime.h>

// AtlasAttention v9 — fused kernel at 3 blocks/CU, exactly-even 768-block grid.
//   prep  : cast X->bf16, transpose Wq/W1/W2, build b1e (unchanged).
//   fused : phase 1: q = Xb@Wqb^T (3-slot ring, vmcnt(3)) -> swizzled bf16 q in LDS.
//           phase 2: poly-on-the-fly GEMM2 (2-slot W1 ring, L2-hot) ->
//                    half-slice H ping-pong in LDS -> GEMM3 -> out.
//   LDS 53,248 B/block -> 3 blocks/CU; grid 768 = 256 CUs x 3 (one even round).
//
// ws layout (bytes):
//   Xb   @ 0          : 8192*768 bf16   = 12,582,912
//   Wqb  @ 12,582,912 : 768*768  bf16^T = 1,179,648   (Wqb[n][k])
//   W1b  @ 13,762,560 : 512*256  bf16^T = 262,144     (W1b[n][k])
//   W2b  @ 14,024,704 : 64*512   bf16^T = 65,536      (W2b[m][k])
//   b1e  @ 14,090,240 : 512 f32         = 2,048

typedef unsigned short u16;
typedef __attribute__((ext_vector_type(8))) short short8;
typedef __attribute__((ext_vector_type(4))) float f32x4;
typedef __attribute__((ext_vector_type(4))) u16 u16x4;

__device__ __forceinline__ u16 f2bf(float f) {
    unsigned u = __builtin_bit_cast(unsigned, f);
    u += 0x7FFFu + ((u >> 16) & 1u);   // RNE
    return (u16)(u >> 16);
}

__device__ __forceinline__ unsigned cvtpk_bf16(float lo, float hi) {
    unsigned r;
    asm("v_cvt_pk_bf16_f32 %0, %1, %2" : "=v"(r) : "v"(lo), "v"(hi));
    return r;
}

__device__ __forceinline__ void gl2lds16(const void* g, void* l) {
    __builtin_amdgcn_global_load_lds(
        (const __attribute__((address_space(1))) unsigned int*)g,
        (__attribute__((address_space(3))) unsigned int*)l, 16, 0, 0);
}

// lgkmcnt(0) ALWAYS included: a wave's LDS reads complete before it passes a barrier.
#define WAIT_VM_LGKM_BAR(N) \
    asm volatile("s_waitcnt vmcnt(" #N ") lgkmcnt(0)\n\ts_barrier" ::: "memory")
#define WAIT_LGKM_BAR() \
    asm volatile("s_waitcnt lgkmcnt(0)\n\ts_barrier" ::: "memory")

// ---------------- fused prep kernel (unchanged, proven) ----------------
__global__ __launch_bounds__(256)
void prep(const float* __restrict__ X, u16* __restrict__ Xb,
          const float* __restrict__ Wq, u16* __restrict__ Wqb,
          const float* __restrict__ W1, u16* __restrict__ W1b,
          const float* __restrict__ W2, u16* __restrict__ W2b,
          const float* __restrict__ b1, const float* __restrict__ coeffs,
          float* __restrict__ b1e)
{
    __shared__ float t[32][33];
    const int b = blockIdx.x, tid = threadIdx.x;

    if (b < 6144) {                       // ---- cast X ----
        const int i = b * 256 + tid;
        float4 v = reinterpret_cast<const float4*>(X)[i];
        u16x4 o = {f2bf(v.x), f2bf(v.y), f2bf(v.z), f2bf(v.w)};
        reinterpret_cast<u16x4*>(Xb)[i] = o;
    } else if (b < 6880) {                // ---- transposes ----
        const float* in; u16* out; int R, Cin, bx, by;
        int lb = b - 6144;
        if (lb < 576)      { in = Wq; out = Wqb; R = 768; Cin = 768; bx = lb % 24; by = lb / 24; }
        else if (lb < 704) { lb -= 576; in = W1; out = W1b; R = 256; Cin = 512; bx = lb % 16; by = lb / 16; }
        else               { lb -= 704; in = W2; out = W2b; R = 512; Cin = 256; bx = lb % 2;  by = lb / 2; }
        const int c0 = bx * 32, r0 = by * 32;
        const int tx = tid & 31, ty = tid >> 5;
        #pragma unroll
        for (int j = 0; j < 32; j += 8)
            t[ty + j][tx] = in[(size_t)(r0 + ty + j) * Cin + c0 + tx];
        __syncthreads();
        #pragma unroll
        for (int j = 0; j < 32; j += 8)
            out[(size_t)(c0 + ty + j) * R + r0 + tx] = f2bf(t[tx][ty + j]);
    } else {                              // ---- b1e ----
        const int n = (b - 6880) * 256 + tid;
        float s = 0.f;
        #pragma unroll 8
        for (int k = 0; k < 64; ++k) s += W1[k * 512 + n];
        b1e[n] = b1[n] + coeffs[0] * s;
    }
}

// ---------------- fused kernel ----------------
// grid (128, 6), 256 threads, LDS 53,248 B -> 3 blocks/CU (grid = 256 CU x 3).
//   qt    @ u16[0]      : [128][64] q bf16, 16B-group XOR swizzle (grp ^= (row>>1)&7)
//   ring1 @ u16[8192]   : phase 1, 3 x 6144 (Xs[64][32] + Ws[128][32])
//   ring2 @ u16[8192]   : phase 2, 2 x 4096 (W1 chunk [128][32])   (aliases ring1)
//   HsH   @ u16[16384]  : 2 x 4096 half-H slice (128 tok x 64 nH, swizzled slots)

__global__ __launch_bounds__(256, 3)
void fused(const u16* __restrict__ Xb, const u16* __restrict__ Wqb,
           const float* __restrict__ coeffs,
           const u16* __restrict__ W1t, const float* __restrict__ b1e,
           const u16* __restrict__ W2t, const float* __restrict__ b2,
           float* __restrict__ out)
{
    __shared__ u16 shm[26624];   // 53,248 B

    const int tid = threadIdx.x;
    const int w = tid >> 6, lane = tid & 63;
    const int lrow = lane >> 2, lslot = lane & 3;
    const int m16 = lane & 15, quad = lane >> 4;
    const int w0 = w & 1, w1 = w >> 1;
    const int tok0 = blockIdx.x * 64;
    const int bn = blockIdx.y * 128;
    const int h0 = blockIdx.y * 2;

    const float c1 = coeffs[1], c2 = coeffs[2], c3 = coeffs[3];

    u16* const qt    = shm;            // [128][64] swizzled
    u16* const ring1 = shm + 8192;
    u16* const ring2 = shm + 8192;
    u16* const HsH   = shm + 16384;

    // ================= phase 1: q = Xb @ Wqb^T =================
    f32x4 acc[4][2];
    #pragma unroll
    for (int i = 0; i < 4; ++i)
        #pragma unroll
        for (int j = 0; j < 2; ++j)
            acc[i][j] = (f32x4){0.f, 0.f, 0.f, 0.f};

    auto stage1 = [&](int slot, int g) {   // 3 loads/thread
        const int k0 = g * 32;
        u16* Xs = ring1 + slot * 6144;
        u16* Ws = Xs + 2048;
        {
            const int row = w * 16 + lrow;
            const int cc = lslot ^ ((row >> 2) & 3);
            gl2lds16(Xb + (size_t)(tok0 + row) * 768 + k0 + cc * 8, &Xs[row * 32 + lslot * 8]);
        }
        #pragma unroll
        for (int i = 0; i < 2; ++i) {
            const int row = (w * 2 + i) * 16 + lrow;
            const int cc = lslot ^ ((row >> 2) & 3);
            gl2lds16(Wqb + (size_t)(bn + row) * 768 + k0 + cc * 8, &Ws[row * 32 + lslot * 8]);
        }
    };

    stage1(0, 0);
    stage1(1, 1);

    #pragma unroll 1
    for (int g = 0; g < 24; ++g) {
        WAIT_VM_LGKM_BAR(3);                          // chunk g landed; slot (g-1)%3 free
        stage1((g + 2) % 3, (g + 2 <= 23) ? g + 2 : 23);
        const u16* Xs = ring1 + (g % 3) * 6144;
        const u16* Ws = Xs + 2048;
        short8 a[4], b[2];
        #pragma unroll
        for (int i = 0; i < 4; ++i) {
            const int row = w0 * 64 + i * 16 + m16;    // n local
            const int ss = quad ^ ((row >> 2) & 3);
            a[i] = *reinterpret_cast<const short8*>(&Ws[row * 32 + ss * 8]);
        }
        #pragma unroll
        for (int j = 0; j < 2; ++j) {
            const int row = w1 * 32 + j * 16 + m16;    // token local
            const int ss = quad ^ ((row >> 2) & 3);
            b[j] = *reinterpret_cast<const short8*>(&Xs[row * 32 + ss * 8]);
        }
        __builtin_amdgcn_s_setprio(1);
        #pragma unroll
        for (int i = 0; i < 4; ++i)
            #pragma unroll
            for (int j = 0; j < 2; ++j)
                acc[i][j] = __builtin_amdgcn_mfma_f32_16x16x32_bf16(a[i], b[j], acc[i][j], 0, 0, 0);
        __builtin_amdgcn_s_setprio(0);
    }

    // phase boundary: drain ring dummies + all LDS reads, then barrier
    asm volatile("s_waitcnt vmcnt(0) lgkmcnt(0)\n\ts_barrier" ::: "memory");

    // ---- early phase-2 staging (overlaps q drain) ----
    auto stage2 = [&](int slot, int g) {   // 2 loads/thread (W1 chunk only)
        const int s = g / 6, c = g % 6;
        u16* W1s = ring2 + slot * 4096;
        #pragma unroll
        for (int i = 0; i < 2; ++i) {
            const int row = (w * 2 + i) * 16 + lrow;
            const int cc = lslot ^ ((row >> 2) & 3);
            gl2lds16(W1t + (size_t)(s * 128 + row) * 256 + 64 + c * 32 + cc * 8,
                     &W1s[row * 32 + lslot * 8]);
        }
    };
    stage2(0, 0);

    // ---- q drain: qt row l, 16B-group G=d0>>3 stored at G^((l>>1)&7), half d0&4 ----
    #pragma unroll
    for (int i = 0; i < 4; ++i) {
        #pragma unroll
        for (int j = 0; j < 2; ++j) {
            const int l = (w1 * 32 + j * 16 + m16) * 2 + w0;
            const int d0 = i * 16 + quad * 4;
            const int grp = (d0 >> 3) ^ ((l >> 1) & 7);
            float x0 = fminf(fmaxf(acc[i][j][0], -10.f), 10.f);
            float x1 = fminf(fmaxf(acc[i][j][1], -10.f), 10.f);
            float x2 = fminf(fmaxf(acc[i][j][2], -10.f), 10.f);
            float x3 = fminf(fmaxf(acc[i][j][3], -10.f), 10.f);
            uint2 v;
            v.x = cvtpk_bf16(x0, x1);
            v.y = cvtpk_bf16(x2, x3);
            *reinterpret_cast<uint2*>(&qt[l * 64 + grp * 8 + (d0 & 7)]) = v;
        }
    }

    // ================= phase 2: out = relu(poly(q)@W1^T + b1e) @ W2^T + b2 =======
    short8 b3s[4][2];                 // W2 fragments for current slice
    auto loadW2 = [&](int s) {
        #pragma unroll
        for (int c = 0; c < 4; ++c)
            #pragma unroll
            for (int j = 0; j < 2; ++j)
                b3s[c][j] = *reinterpret_cast<const short8*>(
                    W2t + (size_t)(w1 * 32 + j * 16 + m16) * 512 + s * 128 + c * 32 + quad * 8);
    };

    f32x4 accO[4][2];
    #pragma unroll
    for (int i = 0; i < 4; ++i)
        #pragma unroll
        for (int j = 0; j < 2; ++j)
            accO[i][j] = (f32x4){0.f, 0.f, 0.f, 0.f};

    int c = 0;
    #pragma unroll 1
    for (int s = 0; s < 4; ++s) {
        f32x4 accH[4][4];
        #pragma unroll
        for (int i = 0; i < 4; ++i)
            #pragma unroll
            for (int j = 0; j < 4; ++j)
                accH[i][j] = (f32x4){0.f, 0.f, 0.f, 0.f};

        #pragma unroll 1
        for (int c6 = 0; c6 < 6; ++c6, ++c) {
            WAIT_VM_LGKM_BAR(0);              // chunk c staged; slot readers done
            if (c < 23) stage2((c + 1) & 1, c + 1);
            if (c6 == 0) loadW2(s);           // consumed >=5 windows later
            const u16* W1s = ring2 + (c & 1) * 4096;
            short8 af[4], bf[4];
            #pragma unroll
            for (int i = 0; i < 4; ++i) {
                const int row = w0 * 64 + i * 16 + m16;          // nH local
                const int ss = quad ^ ((row >> 2) & 3);
                af[i] = *reinterpret_cast<const short8*>(&W1s[row * 32 + ss * 8]);
            }
            #pragma unroll
            for (int j = 0; j < 4; ++j) {
                const int row = w1 * 64 + j * 16 + m16;          // flat-local row
                const int grp = ((c & 1) * 4 + quad) ^ ((row >> 1) & 7);
                short8 qv = *reinterpret_cast<const short8*>(&qt[row * 64 + grp * 8]);
                float y[8];
                #pragma unroll
                for (int e = 0; e < 8; ++e) {
                    float x = __builtin_bit_cast(float, ((unsigned)(u16)qv[e]) << 16);
                    if (c6 < 2)      y[e] = c1 * x;
                    else if (c6 < 4) y[e] = c2 * (x * x);
                    else             y[e] = (c3 * (x * x)) * x;
                }
                uint4 pk;
                pk.x = cvtpk_bf16(y[0], y[1]);
                pk.y = cvtpk_bf16(y[2], y[3]);
                pk.z = cvtpk_bf16(y[4], y[5]);
                pk.w = cvtpk_bf16(y[6], y[7]);
                bf[j] = __builtin_bit_cast(short8, pk);
            }
            __builtin_amdgcn_s_setprio(1);
            #pragma unroll
            for (int i = 0; i < 4; ++i)
                #pragma unroll
                for (int j = 0; j < 4; ++j)
                    accH[i][j] = __builtin_amdgcn_mfma_f32_16x16x32_bf16(af[i], bf[j], accH[i][j], 0, 0, 0);
            __builtin_amdgcn_s_setprio(0);
        }
        // note: window 5 already staged next slice's first chunk -> lands during drains

        // ---- half-slice ping-pong: drain h -> GEMM3 h (h = 0: nH 0-63, 1: 64-127) ----
        #pragma unroll
        for (int h = 0; h < 2; ++h) {
            if (h == 1) { WAIT_LGKM_BAR(); }      // GEMM3(0) readers done before overwrite
            if (w0 == h) {                        // this wave's accH covers nH half h
                #pragma unroll
                for (int i = 0; i < 4; ++i) {
                    const int lb = w0 * 64 + i * 16 + quad * 4;
                    const f32x4 bv = *reinterpret_cast<const f32x4*>(&b1e[s * 128 + lb]);
                    const int slot = (lb >> 5) & 1;
                    #pragma unroll
                    for (int j = 0; j < 4; ++j) {
                        const int tc = w1 * 64 + j * 16 + m16;
                        const float h0v = fmaxf(accH[i][j][0] + bv[0], 0.f);
                        const float h1v = fmaxf(accH[i][j][1] + bv[1], 0.f);
                        const float h2v = fmaxf(accH[i][j][2] + bv[2], 0.f);
                        const float h3v = fmaxf(accH[i][j][3] + bv[3], 0.f);
                        uint2 v;
                        v.x = cvtpk_bf16(h0v, h1v);
                        v.y = cvtpk_bf16(h2v, h3v);
                        const int sl = ((lb >> 3) & 3) ^ ((tc >> 2) & 3);
                        *reinterpret_cast<uint2*>(&HsH[slot * 4096 + tc * 32 + sl * 8 + (lb & 7)]) = v;
                    }
                }
            }
            WAIT_LGKM_BAR();                      // half-H visible to all waves

            __builtin_amdgcn_s_setprio(1);
            #pragma unroll
            for (int c2 = 0; c2 < 2; ++c2) {
                short8 a3[4];
                #pragma unroll
                for (int i = 0; i < 4; ++i) {
                    const int tr = w0 * 64 + i * 16 + m16;       // flat-local row
                    const int ss = quad ^ ((tr >> 2) & 3);
                    a3[i] = *reinterpret_cast<const short8*>(&HsH[c2 * 4096 + tr * 32 + ss * 8]);
                }
                #pragma unroll
                for (int i = 0; i < 4; ++i)
                    #pragma unroll
                    for (int j = 0; j < 2; ++j)
                        accO[i][j] = __builtin_amdgcn_mfma_f32_16x16x32_bf16(
                            a3[i], b3s[h * 2 + c2][j], accO[i][j], 0, 0, 0);
            }
            __builtin_amdgcn_s_setprio(0);
        }
        // next slice's window-0 barrier (lgkm0) orders GEMM3(1) reads vs next drain
    }

    // ---- epilogue: out[(tok0 + l/2)*12 + h0 + (l&1)][col] = accO + b2 ----
    #pragma unroll
    for (int j = 0; j < 2; ++j) {
        const int col = w1 * 32 + j * 16 + m16;
        const float bv = b2[col];
        #pragma unroll
        for (int i = 0; i < 4; ++i) {
            #pragma unroll
            for (int r = 0; r < 4; ++r) {
                const int l = w0 * 64 + i * 16 + quad * 4 + r;
                const size_t orow = (size_t)(tok0 + (l >> 1)) * 12 + h0 + (l & 1);
                out[orow * 64 + col] = accO[i][j][r] + bv;
            }
        }
    }
}

// ---------------- host ----------------

extern "C" void kernel_launch(void* const* d_in, const int* in_sizes, int n_in,
                              void* d_out, int out_size, void* d_ws, size_t ws_size,
                              hipStream_t stream) {
    const float* X      = (const float*)d_in[0];
    const float* Wq     = (const float*)d_in[1];
    const float* coeffs = (const float*)d_in[2];
    const float* W1     = (const float*)d_in[3];
    const float* b1     = (const float*)d_in[4];
    const float* W2     = (const float*)d_in[5];
    const float* b2     = (const float*)d_in[6];

    char* ws = (char*)d_ws;
    u16*   Xb  = (u16*)(ws);
    u16*   Wqb = (u16*)(ws + 12582912);
    u16*   W1b = (u16*)(ws + 13762560);
    u16*   W2b = (u16*)(ws + 14024704);
    float* b1e = (float*)(ws + 14090240);

    prep<<<6882, 256, 0, stream>>>(X, Xb, Wq, Wqb, W1, W1b, W2, W2b, b1, coeffs, b1e);

    // one fused kernel: q -> poly (on the fly) -> MLP -> out
    fused<<<dim3(128, 6), 256, 0, stream>>>(Xb, Wqb, coeffs, W1b, b1e, W2b, b2,
                                            (float*)d_out);
}

// Round 9
// 149.883 us; speedup vs baseline: 1.2412x; 1.2412x over previous
//
#include <hip/hip_runtime.h>

// AtlasAttention v10 — v8 (proven 70.4us) + phase-2 window merge (24 -> 12 epochs).
//   prep  : cast X->bf16, transpose Wq/W1/W2, build b1e (unchanged).
//   fused : phase 1: q = Xb@Wqb^T (3-slot ring, vmcnt(3)) -> swizzled bf16 q in LDS.
//           phase 2: 12 windows of K=64 (2 W1 chunks, one poly power each, 4-slot
//           ring), full-Hs drain + GEMM3 per slice (v8 verbatim).
//   LDS exactly 81,920B -> 2 blocks/CU.
//
// ws layout (bytes):
//   Xb   @ 0          : 8192*768 bf16   = 12,582,912
//   Wqb  @ 12,582,912 : 768*768  bf16^T = 1,179,648   (Wqb[n][k])
//   W1b  @ 13,762,560 : 512*256  bf16^T = 262,144     (W1b[n][k])
//   W2b  @ 14,024,704 : 64*512   bf16^T = 65,536      (W2b[m][k])
//   b1e  @ 14,090,240 : 512 f32         = 2,048

typedef unsigned short u16;
typedef __attribute__((ext_vector_type(8))) short short8;
typedef __attribute__((ext_vector_type(4))) float f32x4;
typedef __attribute__((ext_vector_type(4))) u16 u16x4;

__device__ __forceinline__ u16 f2bf(float f) {
    unsigned u = __builtin_bit_cast(unsigned, f);
    u += 0x7FFFu + ((u >> 16) & 1u);   // RNE
    return (u16)(u >> 16);
}

__device__ __forceinline__ unsigned cvtpk_bf16(float lo, float hi) {
    unsigned r;
    asm("v_cvt_pk_bf16_f32 %0, %1, %2" : "=v"(r) : "v"(lo), "v"(hi));
    return r;
}

__device__ __forceinline__ void gl2lds16(const void* g, void* l) {
    __builtin_amdgcn_global_load_lds(
        (const __attribute__((address_space(1))) unsigned int*)g,
        (__attribute__((address_space(3))) unsigned int*)l, 16, 0, 0);
}

// lgkmcnt(0) ALWAYS included: a wave's LDS reads complete before it passes a barrier.
#define WAIT_VM_LGKM_BAR(N) \
    asm volatile("s_waitcnt vmcnt(" #N ") lgkmcnt(0)\n\ts_barrier" ::: "memory")
#define WAIT_LGKM_BAR() \
    asm volatile("s_waitcnt lgkmcnt(0)\n\ts_barrier" ::: "memory")

// ---------------- fused prep kernel (unchanged, proven) ----------------
__global__ __launch_bounds__(256)
void prep(const float* __restrict__ X, u16* __restrict__ Xb,
          const float* __restrict__ Wq, u16* __restrict__ Wqb,
          const float* __restrict__ W1, u16* __restrict__ W1b,
          const float* __restrict__ W2, u16* __restrict__ W2b,
          const float* __restrict__ b1, const float* __restrict__ coeffs,
          float* __restrict__ b1e)
{
    __shared__ float t[32][33];
    const int b = blockIdx.x, tid = threadIdx.x;

    if (b < 6144) {                       // ---- cast X ----
        const int i = b * 256 + tid;
        float4 v = reinterpret_cast<const float4*>(X)[i];
        u16x4 o = {f2bf(v.x), f2bf(v.y), f2bf(v.z), f2bf(v.w)};
        reinterpret_cast<u16x4*>(Xb)[i] = o;
    } else if (b < 6880) {                // ---- transposes ----
        const float* in; u16* out; int R, Cin, bx, by;
        int lb = b - 6144;
        if (lb < 576)      { in = Wq; out = Wqb; R = 768; Cin = 768; bx = lb % 24; by = lb / 24; }
        else if (lb < 704) { lb -= 576; in = W1; out = W1b; R = 256; Cin = 512; bx = lb % 16; by = lb / 16; }
        else               { lb -= 704; in = W2; out = W2b; R = 512; Cin = 256; bx = lb % 2;  by = lb / 2; }
        const int c0 = bx * 32, r0 = by * 32;
        const int tx = tid & 31, ty = tid >> 5;
        #pragma unroll
        for (int j = 0; j < 32; j += 8)
            t[ty + j][tx] = in[(size_t)(r0 + ty + j) * Cin + c0 + tx];
        __syncthreads();
        #pragma unroll
        for (int j = 0; j < 32; j += 8)
            out[(size_t)(c0 + ty + j) * R + r0 + tx] = f2bf(t[tx][ty + j]);
    } else {                              // ---- b1e ----
        const int n = (b - 6880) * 256 + tid;
        float s = 0.f;
        #pragma unroll 8
        for (int k = 0; k < 64; ++k) s += W1[k * 512 + n];
        b1e[n] = b1[n] + coeffs[0] * s;
    }
}

// ---------------- fused kernel ----------------
// grid (128, 6), 256 threads, LDS 81,920B -> 2 blocks/CU.
//   qt    @ u16[0]      : [128][64] q bf16, 16B-group XOR swizzle (grp ^= (row>>1)&7)
//   ring1 @ u16[8192]   : phase 1, 3 x 6144 (Xs[64][32] + Ws[128][32]) -> [8192,26624)
//   ring2 @ u16[8192]   : phase 2, 4 x 4096 (W1 chunk [128][32])       -> [8192,24576)
//   HsB   @ u16[24576]  : 4 x 4096 H slice (aliases ring1 tail; phase-separated)

__global__ __launch_bounds__(256, 2)
void fused(const u16* __restrict__ Xb, const u16* __restrict__ Wqb,
           const float* __restrict__ coeffs,
           const u16* __restrict__ W1t, const float* __restrict__ b1e,
           const u16* __restrict__ W2t, const float* __restrict__ b2,
           float* __restrict__ out)
{
    __shared__ u16 shm[40960];   // 81,920 B

    const int tid = threadIdx.x;
    const int w = tid >> 6, lane = tid & 63;
    const int lrow = lane >> 2, lslot = lane & 3;
    const int m16 = lane & 15, quad = lane >> 4;
    const int w0 = w & 1, w1 = w >> 1;
    const int tok0 = blockIdx.x * 64;
    const int bn = blockIdx.y * 128;
    const int h0 = blockIdx.y * 2;

    const float c1 = coeffs[1], c2 = coeffs[2], c3 = coeffs[3];

    u16* const qt    = shm;            // [128][64] swizzled
    u16* const ring1 = shm + 8192;
    u16* const ring2 = shm + 8192;
    u16* const HsB   = shm + 24576;

    // ================= phase 1: q = Xb @ Wqb^T (v8 verbatim) =================
    f32x4 acc[4][2];
    #pragma unroll
    for (int i = 0; i < 4; ++i)
        #pragma unroll
        for (int j = 0; j < 2; ++j)
            acc[i][j] = (f32x4){0.f, 0.f, 0.f, 0.f};

    auto stage1 = [&](int slot, int g) {   // 3 loads/thread
        const int k0 = g * 32;
        u16* Xs = ring1 + slot * 6144;
        u16* Ws = Xs + 2048;
        {
            const int row = w * 16 + lrow;
            const int cc = lslot ^ ((row >> 2) & 3);
            gl2lds16(Xb + (size_t)(tok0 + row) * 768 + k0 + cc * 8, &Xs[row * 32 + lslot * 8]);
        }
        #pragma unroll
        for (int i = 0; i < 2; ++i) {
            const int row = (w * 2 + i) * 16 + lrow;
            const int cc = lslot ^ ((row >> 2) & 3);
            gl2lds16(Wqb + (size_t)(bn + row) * 768 + k0 + cc * 8, &Ws[row * 32 + lslot * 8]);
        }
    };

    stage1(0, 0);
    stage1(1, 1);

    #pragma unroll 1
    for (int g = 0; g < 24; ++g) {
        WAIT_VM_LGKM_BAR(3);                          // chunk g landed; slot (g-1)%3 free
        stage1((g + 2) % 3, (g + 2 <= 23) ? g + 2 : 23);
        const u16* Xs = ring1 + (g % 3) * 6144;
        const u16* Ws = Xs + 2048;
        short8 a[4], b[2];
        #pragma unroll
        for (int i = 0; i < 4; ++i) {
            const int row = w0 * 64 + i * 16 + m16;    // n local
            const int ss = quad ^ ((row >> 2) & 3);
            a[i] = *reinterpret_cast<const short8*>(&Ws[row * 32 + ss * 8]);
        }
        #pragma unroll
        for (int j = 0; j < 2; ++j) {
            const int row = w1 * 32 + j * 16 + m16;    // token local
            const int ss = quad ^ ((row >> 2) & 3);
            b[j] = *reinterpret_cast<const short8*>(&Xs[row * 32 + ss * 8]);
        }
        __builtin_amdgcn_s_setprio(1);
        #pragma unroll
        for (int i = 0; i < 4; ++i)
            #pragma unroll
            for (int j = 0; j < 2; ++j)
                acc[i][j] = __builtin_amdgcn_mfma_f32_16x16x32_bf16(a[i], b[j], acc[i][j], 0, 0, 0);
        __builtin_amdgcn_s_setprio(0);
    }

    // phase boundary: drain ring dummies + all LDS reads, then barrier
    asm volatile("s_waitcnt vmcnt(0) lgkmcnt(0)\n\ts_barrier" ::: "memory");

    // ---- phase-2 staging lambda + early stage of chunks 0,1 (overlaps q drain) ----
    auto stage2 = [&](int slot, int g) {   // 2 loads/thread (W1 chunk only)
        const int sg = g / 6, cg = g % 6;
        u16* W1s = ring2 + slot * 4096;
        #pragma unroll
        for (int i = 0; i < 2; ++i) {
            const int row = (w * 2 + i) * 16 + lrow;
            const int cc = lslot ^ ((row >> 2) & 3);
            gl2lds16(W1t + (size_t)(sg * 128 + row) * 256 + 64 + cg * 32 + cc * 8,
                     &W1s[row * 32 + lslot * 8]);
        }
    };
    auto stage2c = [&](int slot, int gg) {
        stage2(slot, (gg <= 23) ? gg : 23);   // tail dummies keep vmcnt uniform
    };

    stage2(0, 0);
    stage2(1, 1);

    // ---- q drain: row l, logical 16B-group G=d0>>3 stored at G^((l>>1)&7) ----
    #pragma unroll
    for (int i = 0; i < 4; ++i) {
        #pragma unroll
        for (int j = 0; j < 2; ++j) {
            const int l = (w1 * 32 + j * 16 + m16) * 2 + w0;
            const int d0 = i * 16 + quad * 4;
            const int grp = (d0 >> 3) ^ ((l >> 1) & 7);
            float x0 = fminf(fmaxf(acc[i][j][0], -10.f), 10.f);
            float x1 = fminf(fmaxf(acc[i][j][1], -10.f), 10.f);
            float x2 = fminf(fmaxf(acc[i][j][2], -10.f), 10.f);
            float x3 = fminf(fmaxf(acc[i][j][3], -10.f), 10.f);
            uint2 v;
            v.x = cvtpk_bf16(x0, x1);
            v.y = cvtpk_bf16(x2, x3);
            *reinterpret_cast<uint2*>(&qt[l * 64 + grp * 8 + (d0 & 7)]) = v;
        }
    }

    // ================= phase 2: out = relu(poly(q)@W1^T + b1e) @ W2^T + b2 =======
    short8 b3s[4][2];                 // W2 fragments for current slice
    auto loadW2 = [&](int s) {
        #pragma unroll
        for (int c = 0; c < 4; ++c)
            #pragma unroll
            for (int j = 0; j < 2; ++j)
                b3s[c][j] = *reinterpret_cast<const short8*>(
                    W2t + (size_t)(w1 * 32 + j * 16 + m16) * 512 + s * 128 + c * 32 + quad * 8);
    };

    f32x4 accO[4][2];
    #pragma unroll
    for (int i = 0; i < 4; ++i)
        #pragma unroll
        for (int j = 0; j < 2; ++j)
            accO[i][j] = (f32x4){0.f, 0.f, 0.f, 0.f};

    #pragma unroll 1
    for (int s = 0; s < 4; ++s) {
        f32x4 accH[4][4];
        #pragma unroll
        for (int i = 0; i < 4; ++i)
            #pragma unroll
            for (int j = 0; j < 4; ++j)
                accH[i][j] = (f32x4){0.f, 0.f, 0.f, 0.f};

        // one merged window: chunks cb (parity 0, qt cols 0-31), cb+1 (parity 1),
        // single poly power pw; 32 MFMAs.
        auto computePair = [&](int slotA, int slotB, int pw) {
            short8 afA[4], afB[4], bfA[4], bfB[4];
            #pragma unroll
            for (int i = 0; i < 4; ++i) {
                const int row = w0 * 64 + i * 16 + m16;          // nH local
                const int ss = quad ^ ((row >> 2) & 3);
                afA[i] = *reinterpret_cast<const short8*>(&ring2[slotA * 4096 + row * 32 + ss * 8]);
                afB[i] = *reinterpret_cast<const short8*>(&ring2[slotB * 4096 + row * 32 + ss * 8]);
            }
            #pragma unroll
            for (int j = 0; j < 4; ++j) {
                const int row = w1 * 64 + j * 16 + m16;          // flat-local row
                const int sw = (row >> 1) & 7;
                short8 qv0 = *reinterpret_cast<const short8*>(&qt[row * 64 + ((quad) ^ sw) * 8]);
                short8 qv1 = *reinterpret_cast<const short8*>(&qt[row * 64 + ((4 + quad) ^ sw) * 8]);
                float y0[8], y1[8];
                #pragma unroll
                for (int e = 0; e < 8; ++e) {
                    float xa = __builtin_bit_cast(float, ((unsigned)(u16)qv0[e]) << 16);
                    float xb = __builtin_bit_cast(float, ((unsigned)(u16)qv1[e]) << 16);
                    if (pw == 1)      { y0[e] = c1 * xa;             y1[e] = c1 * xb; }
                    else if (pw == 2) { y0[e] = c2 * (xa * xa);      y1[e] = c2 * (xb * xb); }
                    else              { y0[e] = (c3 * (xa * xa)) * xa; y1[e] = (c3 * (xb * xb)) * xb; }
                }
                uint4 pkA, pkB;
                pkA.x = cvtpk_bf16(y0[0], y0[1]); pkA.y = cvtpk_bf16(y0[2], y0[3]);
                pkA.z = cvtpk_bf16(y0[4], y0[5]); pkA.w = cvtpk_bf16(y0[6], y0[7]);
                pkB.x = cvtpk_bf16(y1[0], y1[1]); pkB.y = cvtpk_bf16(y1[2], y1[3]);
                pkB.z = cvtpk_bf16(y1[4], y1[5]); pkB.w = cvtpk_bf16(y1[6], y1[7]);
                bfA[j] = __builtin_bit_cast(short8, pkA);
                bfB[j] = __builtin_bit_cast(short8, pkB);
            }
            __builtin_amdgcn_s_setprio(1);
            #pragma unroll
            for (int i = 0; i < 4; ++i)
                #pragma unroll
                for (int j = 0; j < 4; ++j) {
                    accH[i][j] = __builtin_amdgcn_mfma_f32_16x16x32_bf16(afA[i], bfA[j], accH[i][j], 0, 0, 0);
                    accH[i][j] = __builtin_amdgcn_mfma_f32_16x16x32_bf16(afB[i], bfB[j], accH[i][j], 0, 0, 0);
                }
            __builtin_amdgcn_s_setprio(0);
        };

        const int cb = s * 6;   // global chunk base; cb even and 6s % 4 alternates 0/2
        // window A: chunks cb, cb+1 (power 1); stage cb+2,cb+3; W2 loads issued here
        WAIT_VM_LGKM_BAR(0);
        stage2c((cb + 2) & 3, cb + 2);
        stage2c((cb + 3) & 3, cb + 3);
        loadW2(s);
        computePair(cb & 3, (cb + 1) & 3, 1);
        // window B: chunks cb+2, cb+3 (power 2); W2's 8 loads may stay in flight
        WAIT_VM_LGKM_BAR(8);
        stage2c((cb + 4) & 3, cb + 4);
        stage2c((cb + 5) & 3, cb + 5);
        computePair((cb + 2) & 3, (cb + 3) & 3, 2);
        // window C: chunks cb+4, cb+5 (power 3)
        WAIT_VM_LGKM_BAR(0);
        stage2c((cb + 6) & 3, cb + 6);
        stage2c((cb + 7) & 3, cb + 7);
        computePair((cb + 4) & 3, (cb + 5) & 3, 3);

        // ---- drain: HsB[tok][nH] = bf16(relu(accH + b1e)) (v8 verbatim) ----
        #pragma unroll
        for (int i = 0; i < 4; ++i) {
            const int lb = w0 * 64 + i * 16 + quad * 4;          // nH local base
            const f32x4 bv = *reinterpret_cast<const f32x4*>(&b1e[s * 128 + lb]);
            const int hc = lb >> 5;
            #pragma unroll
            for (int j = 0; j < 4; ++j) {
                const int tc = w1 * 64 + j * 16 + m16;           // flat-local row
                const float h0v = fmaxf(accH[i][j][0] + bv[0], 0.f);
                const float h1v = fmaxf(accH[i][j][1] + bv[1], 0.f);
                const float h2v = fmaxf(accH[i][j][2] + bv[2], 0.f);
                const float h3v = fmaxf(accH[i][j][3] + bv[3], 0.f);
                uint2 v;
                v.x = cvtpk_bf16(h0v, h1v);
                v.y = cvtpk_bf16(h2v, h3v);
                const int sl = ((lb >> 3) & 3) ^ ((tc >> 2) & 3);
                *reinterpret_cast<uint2*>(&HsB[hc * 4096 + tc * 32 + sl * 8 + (lb & 7)]) = v;
            }
        }

        WAIT_LGKM_BAR();   // Hs visible; ring prefetches stay in flight

        // ---- GEMM3 partial: accO += Hs @ W2slice^T (v8 verbatim) ----
        __builtin_amdgcn_s_setprio(1);
        #pragma unroll
        for (int c = 0; c < 4; ++c) {
            short8 a3[4];
            #pragma unroll
            for (int i = 0; i < 4; ++i) {
                const int tr = w0 * 64 + i * 16 + m16;           // flat-local row
                const int ss = quad ^ ((tr >> 2) & 3);
                a3[i] = *reinterpret_cast<const short8*>(&HsB[c * 4096 + tr * 32 + ss * 8]);
            }
            #pragma unroll
            for (int i = 0; i < 4; ++i)
                #pragma unroll
                for (int j = 0; j < 2; ++j)
                    accO[i][j] = __builtin_amdgcn_mfma_f32_16x16x32_bf16(a3[i], b3s[c][j], accO[i][j], 0, 0, 0);
        }
        __builtin_amdgcn_s_setprio(0);
        // next slice's window-A WAIT (lgkm0 + barrier) orders these reads vs next drain
    }

    asm volatile("s_waitcnt vmcnt(0)" ::: "memory");   // retire dummy stages

    // ---- epilogue: out[(tok0 + l/2)*12 + h0 + (l&1)][col] = accO + b2 ----
    #pragma unroll
    for (int j = 0; j < 2; ++j) {
        const int col = w1 * 32 + j * 16 + m16;
        const float bv = b2[col];
        #pragma unroll
        for (int i = 0; i < 4; ++i) {
            #pragma unroll
            for (int r = 0; r < 4; ++r) {
                const int l = w0 * 64 + i * 16 + quad * 4 + r;
                const size_t orow = (size_t)(tok0 + (l >> 1)) * 12 + h0 + (l & 1);
                out[orow * 64 + col] = accO[i][j][r] + bv;
            }
        }
    }
}

// ---------------- host ----------------

extern "C" void kernel_launch(void* const* d_in, const int* in_sizes, int n_in,
                              void* d_out, int out_size, void* d_ws, size_t ws_size,
                              hipStream_t stream) {
    const float* X      = (const float*)d_in[0];
    const float* Wq     = (const float*)d_in[1];
    const float* coeffs = (const float*)d_in[2];
    const float* W1     = (const float*)d_in[3];
    const float* b1     = (const float*)d_in[4];
    const float* W2     = (const float*)d_in[5];
    const float* b2     = (const float*)d_in[6];

    char* ws = (char*)d_ws;
    u16*   Xb  = (u16*)(ws);
    u16*   Wqb = (u16*)(ws + 12582912);
    u16*   W1b = (u16*)(ws + 13762560);
    u16*   W2b = (u16*)(ws + 14024704);
    float* b1e = (float*)(ws + 14090240);

    prep<<<6882, 256, 0, stream>>>(X, Xb, Wq, Wqb, W1, W1b, W2, W2b, b1, coeffs, b1e);

    // one fused kernel: q -> poly (on the fly) -> MLP -> out
    fused<<<dim3(128, 6), 256, 0, stream>>>(Xb, Wqb, coeffs, W1b, b1e, W2b, b2,
                                            (float*)d_out);
}